// Round 8
// baseline (391.666 us; speedup 1.0000x reference)
//
#include <hip/hip_runtime.h>
#include <hip/hip_fp16.h>

// GCN 3-layer: x -> GCNConv(W1)+BN+ReLU -> GCNConv(W2)+BN+ReLU -> GCNConv(W3)
// CSR built once: 1 u64 atomic/edge -> {count, weighted-degree, in-bucket rank},
// atomic-free fill. Edge record packed to u32 {src:16 | norm fixed2^15:16}.
// Dense transform: MFMA f16 16x16x32, wave = 16 nodes x F, fp32 accum; output
// written into 8 per-XCD feature-shard arrays (rows padded to 32B so a gather
// touches exactly one 128B line; shard = 1.6MB < 4MB per-XCD L2).
// Aggregation: shard = blockIdx&7 (XCD-pinned under round-robin dispatch),
// thread = (node, shard): fp16 gather all-L2-hit, fp32 accum, fused bias/BN/ReLU.
// R5 lesson honored: shards are physically separate, line-aligned arrays.

constexpr float BN_EPS = 1e-5f;
constexpr float FIXED_SCALE = 33554432.0f;        // 2^25 (weighted degree accum)
constexpr float INV_FIXED_SCALE = 1.0f / 33554432.0f;
constexpr float NORM_SCALE = 32768.0f;            // 2^15 (edge norm quant)
constexpr float INV_NORM_SCALE = 1.0f / 32768.0f;

typedef _Float16 f16x8 __attribute__((ext_vector_type(8)));
typedef float f32x4 __attribute__((ext_vector_type(4)));

// ---------------- graph build + weight convert (fused) ----------------

// blocks [0, deg_b): one u64 atomic per edge; old>>32 = rank in dest bucket.
// blocks [deg_b, ...): fp32->fp16 convert of W1|W2|W3 into wh (concatenated).
__global__ void k_deg_cvt(const int* __restrict__ col_idx, const float* __restrict__ ew,
                          unsigned long long* packed, int* rank, int e_cnt, int deg_b,
                          const float* __restrict__ W1, const float* __restrict__ W2,
                          const float* __restrict__ W3, _Float16* __restrict__ wh,
                          int w1n4, int w2n4, int w3n4) {
    if (blockIdx.x < deg_b) {
        int e = blockIdx.x * 256 + threadIdx.x;
        if (e < e_cnt) {
            int c = col_idx[e];
            unsigned int wfix = (unsigned int)(ew[e] * FIXED_SCALE + 0.5f);
            unsigned long long inc = (1ull << 32) | (unsigned long long)wfix;
            unsigned long long old = atomicAdd(&packed[c], inc);
            rank[e] = (int)(old >> 32);
        }
    } else {
        int i = (blockIdx.x - deg_b) * 256 + threadIdx.x;   // float4 index
        int total = w1n4 + w2n4 + w3n4;
        if (i < total) {
            const float* src; int off;
            if (i < w1n4) { src = W1; off = i; }
            else if (i < w1n4 + w2n4) { src = W2; off = i - w1n4; }
            else { src = W3; off = i - w1n4 - w2n4; }
            float4 v = ((const float4*)src)[off];
            __half2 h0 = __floats2half2_rn(v.x, v.y);
            __half2 h1 = __floats2half2_rn(v.z, v.w);
            uint2 u = make_uint2(*(unsigned int*)&h0, *(unsigned int*)&h1);
            *(uint2*)(wh + (size_t)i * 4) = u;
        }
    }
}

// block-sum of counts (hi32) + fused dis = rsqrt(1 + wsum)
__global__ void k_scan1(const unsigned long long* __restrict__ packed,
                        int* bsum, float* dis, int n) {
    __shared__ int s[256];
    int i = blockIdx.x * 256 + threadIdx.x;
    int cnt = 0;
    if (i < n) {
        unsigned long long p = packed[i];
        cnt = (int)(p >> 32);
        float wsum = (float)(unsigned int)(p & 0xffffffffull) * INV_FIXED_SCALE;
        dis[i] = rsqrtf(1.0f + wsum);   // self-loop weight 1 included
    }
    s[threadIdx.x] = cnt;
    __syncthreads();
    for (int off = 128; off > 0; off >>= 1) {
        if (threadIdx.x < off) s[threadIdx.x] += s[threadIdx.x + off];
        __syncthreads();
    }
    if (threadIdx.x == 0) bsum[blockIdx.x] = s[0];
}

__global__ void k_scan2(const int* __restrict__ bsum, int* boff, int nb) {
    __shared__ int s[256];
    int t = threadIdx.x;
    int v = (t < nb) ? bsum[t] : 0;
    s[t] = v;
    __syncthreads();
    for (int off = 1; off < 256; off <<= 1) {
        int x = (t >= off) ? s[t - off] : 0;
        __syncthreads();
        s[t] += x;
        __syncthreads();
    }
    if (t < nb) boff[t] = s[t] - v;  // exclusive
}

__global__ void k_scan3(const unsigned long long* __restrict__ packed,
                        const int* __restrict__ boff,
                        int* row_ptr, int n, int e_total) {
    __shared__ int s[256];
    int t = threadIdx.x;
    int i = blockIdx.x * 256 + t;
    int v = (i < n) ? (int)(packed[i] >> 32) : 0;
    s[t] = v;
    __syncthreads();
    for (int off = 1; off < 256; off <<= 1) {
        int x = (t >= off) ? s[t - off] : 0;
        __syncthreads();
        s[t] += x;
        __syncthreads();
    }
    int ex = s[t] - v + boff[blockIdx.x];
    if (i < n) row_ptr[i] = ex;
    if (i == 0) row_ptr[n] = e_total;
}

// atomic-free fill: slot = row_ptr[dest] + rank; record = {src:16 | norm:16}
__global__ void k_fill(const int* __restrict__ row_idx, const int* __restrict__ col_idx,
                       const float* __restrict__ ew, const float* __restrict__ dis,
                       const int* __restrict__ row_ptr, const int* __restrict__ rank,
                       unsigned* ep, int e_cnt) {
    int e = blockIdx.x * 256 + threadIdx.x;
    if (e < e_cnt) {
        int r = row_idx[e];
        int c = col_idx[e];
        float nm = dis[r] * ew[e] * dis[c];
        unsigned q = (unsigned)(nm * NORM_SCALE + 0.5f);
        if (q > 65535u) q = 65535u;
        int p = row_ptr[c] + rank[e];
        ep[p] = ((unsigned)r << 16) | q;
    }
}

// ---------------- dense transform via MFMA f16 ----------------
// Y[n][f] = sum_k X[n][k] * W[f][k]; wave = 16 nodes x F features.
// Output into 8 shard arrays: shard s holds rows of SROW halves (SHW used).

template <int K, int F, int SHW, bool F32IN>
__global__ __launch_bounds__(256) void k_gemm(const void* __restrict__ Xin,
                                              const _Float16* __restrict__ Wh,
                                              _Float16* __restrict__ Ys, int n) {
    constexpr int KT = K / 32;
    constexpr int FT = F / 16;
    constexpr int SROW = (SHW == 12) ? 16 : 8;
    int wave = threadIdx.x >> 6;
    int lane = threadIdx.x & 63;
    int n0 = (blockIdx.x * 4 + wave) * 16;
    if (n0 >= n) return;
    int quad = lane >> 4;
    int r = lane & 15;

    f16x8 a[KT];
    if (F32IN) {
        const float* xr = (const float*)Xin + (size_t)(n0 + r) * K + quad * 8;
#pragma unroll
        for (int kt = 0; kt < KT; ++kt) {
            float4 v0 = *(const float4*)(xr + kt * 32);
            float4 v1 = *(const float4*)(xr + kt * 32 + 4);
            f16x8 t = {(_Float16)v0.x, (_Float16)v0.y, (_Float16)v0.z, (_Float16)v0.w,
                       (_Float16)v1.x, (_Float16)v1.y, (_Float16)v1.z, (_Float16)v1.w};
            a[kt] = t;
        }
    } else {
        const f16x8* xr = (const f16x8*)((const _Float16*)Xin + (size_t)(n0 + r) * K + quad * 8);
#pragma unroll
        for (int kt = 0; kt < KT; ++kt) a[kt] = xr[kt * 4];
    }

    const f16x8* __restrict__ wrow = (const f16x8*)(Wh + (size_t)r * K + quad * 8);

    f32x4 acc[FT];
#pragma unroll
    for (int ft = 0; ft < FT; ++ft) acc[ft] = (f32x4){0.f, 0.f, 0.f, 0.f};

#pragma unroll
    for (int kt = 0; kt < KT; ++kt) {
#pragma unroll
        for (int ft = 0; ft < FT; ++ft) {
            f16x8 b = wrow[(size_t)ft * 2 * K + kt * 4];   // (ft*16*K + kt*32) halves
            acc[ft] = __builtin_amdgcn_mfma_f32_16x16x32_f16(a[kt], b, acc[ft], 0, 0, 0);
        }
    }

    // C/D: col = lane&15 (feature), row = quad*4 + reg (node)
#pragma unroll
    for (int ft = 0; ft < FT; ++ft) {
        int f = ft * 16 + r;
        int s_, off;
        if (SHW == 12) { s_ = f / 12; off = f - s_ * 12; }
        else           { s_ = f >> 3; off = f & 7; }
        _Float16* dst = Ys + (size_t)s_ * n * SROW + off;
#pragma unroll
        for (int reg = 0; reg < 4; ++reg) {
            int row = n0 + quad * 4 + reg;
            dst[(size_t)row * SROW] = (_Float16)acc[ft][reg];
        }
    }
}

// ---------------- aggregation over XCD-pinned shards ----------------

__device__ inline void cvt8(uint4 u, float* f) {
    float2 t;
    t = __half22float2(*(const __half2*)&u.x); f[0] = t.x; f[1] = t.y;
    t = __half22float2(*(const __half2*)&u.y); f[2] = t.x; f[3] = t.y;
    t = __half22float2(*(const __half2*)&u.z); f[4] = t.x; f[5] = t.y;
    t = __half22float2(*(const __half2*)&u.w); f[6] = t.x; f[7] = t.y;
}

__device__ inline void fma8(uint4 u, float w, float* acc) {
    float2 t;
    t = __half22float2(*(const __half2*)&u.x); acc[0] = fmaf(w, t.x, acc[0]); acc[1] = fmaf(w, t.y, acc[1]);
    t = __half22float2(*(const __half2*)&u.y); acc[2] = fmaf(w, t.x, acc[2]); acc[3] = fmaf(w, t.y, acc[3]);
    t = __half22float2(*(const __half2*)&u.z); acc[4] = fmaf(w, t.x, acc[4]); acc[5] = fmaf(w, t.y, acc[5]);
    t = __half22float2(*(const __half2*)&u.w); acc[6] = fmaf(w, t.x, acc[6]); acc[7] = fmaf(w, t.y, acc[7]);
}

__device__ inline void fma4(uint4 u, float w, float* acc) {
    float2 t;
    t = __half22float2(*(const __half2*)&u.x); acc[0] = fmaf(w, t.x, acc[0]); acc[1] = fmaf(w, t.y, acc[1]);
    t = __half22float2(*(const __half2*)&u.y); acc[2] = fmaf(w, t.x, acc[2]); acc[3] = fmaf(w, t.y, acc[3]);
}

template <int F, int SHW, bool BN, bool F32OUT>
__global__ __launch_bounds__(256) void k_aggr(
    const _Float16* __restrict__ Xs, const int* __restrict__ row_ptr,
    const unsigned* __restrict__ ep, const float* __restrict__ dis,
    const float* __restrict__ bias, const float* __restrict__ g,
    const float* __restrict__ beta, const float* __restrict__ m,
    const float* __restrict__ v, void* __restrict__ out, int n) {
    constexpr int SROW = (SHW == 12) ? 16 : 8;
    int s = blockIdx.x & 7;                       // shard -> XCD (heuristic)
    int node = (blockIdx.x >> 3) * 256 + threadIdx.x;
    if (node >= n) return;
    const _Float16* __restrict__ base = Xs + (size_t)s * n * SROW;

    float acc[SHW];
    {
        float d = dis[node];
        float d2 = d * d;
        const _Float16* sp = base + (size_t)node * SROW;
        float t[SHW];
        uint4 u0 = *(const uint4*)sp;
        cvt8(u0, t);
        if (SHW == 12) {
            uint4 u1 = *(const uint4*)(sp + 8);
            float2 w0 = __half22float2(*(const __half2*)&u1.x);
            float2 w1 = __half22float2(*(const __half2*)&u1.y);
            t[8] = w0.x; t[9] = w0.y; t[10] = w1.x; t[11] = w1.y;
        }
#pragma unroll
        for (int j = 0; j < SHW; ++j) acc[j] = d2 * t[j];
    }

    int e0 = row_ptr[node], e1 = row_ptr[node + 1];
    int e = e0;
    for (; e + 4 <= e1; e += 4) {
        unsigned p0 = ep[e + 0], p1 = ep[e + 1], p2 = ep[e + 2], p3 = ep[e + 3];
        const _Float16* r0 = base + (size_t)(p0 >> 16) * SROW;
        const _Float16* r1 = base + (size_t)(p1 >> 16) * SROW;
        const _Float16* r2 = base + (size_t)(p2 >> 16) * SROW;
        const _Float16* r3 = base + (size_t)(p3 >> 16) * SROW;
        uint4 a0 = *(const uint4*)r0;
        uint4 a1 = *(const uint4*)r1;
        uint4 a2 = *(const uint4*)r2;
        uint4 a3 = *(const uint4*)r3;
        float w0 = (float)(p0 & 0xffffu) * INV_NORM_SCALE;
        float w1 = (float)(p1 & 0xffffu) * INV_NORM_SCALE;
        float w2 = (float)(p2 & 0xffffu) * INV_NORM_SCALE;
        float w3 = (float)(p3 & 0xffffu) * INV_NORM_SCALE;
        fma8(a0, w0, acc); fma8(a1, w1, acc); fma8(a2, w2, acc); fma8(a3, w3, acc);
        if (SHW == 12) {
            uint4 b0 = *(const uint4*)(r0 + 8);
            uint4 b1 = *(const uint4*)(r1 + 8);
            uint4 b2 = *(const uint4*)(r2 + 8);
            uint4 b3 = *(const uint4*)(r3 + 8);
            fma4(b0, w0, acc + 8); fma4(b1, w1, acc + 8);
            fma4(b2, w2, acc + 8); fma4(b3, w3, acc + 8);
        }
    }
    for (; e < e1; ++e) {
        unsigned p = ep[e];
        const _Float16* r0 = base + (size_t)(p >> 16) * SROW;
        float w = (float)(p & 0xffffu) * INV_NORM_SCALE;
        uint4 a0 = *(const uint4*)r0;
        fma8(a0, w, acc);
        if (SHW == 12) {
            uint4 b0 = *(const uint4*)(r0 + 8);
            fma4(b0, w, acc + 8);
        }
    }

    int fb = s * SHW;
#pragma unroll
    for (int j = 0; j < SHW; ++j) acc[j] += bias[fb + j];
    if (BN) {
#pragma unroll
        for (int j = 0; j < SHW; ++j) {
            acc[j] = fmaxf((acc[j] - m[fb + j]) * rsqrtf(v[fb + j] + BN_EPS) * g[fb + j]
                           + beta[fb + j], 0.f);
        }
    }

    if (F32OUT) {
        float* op = (float*)out + (size_t)node * F + fb;
        *(float4*)(op + 0) = make_float4(acc[0], acc[1], acc[2], acc[3]);
        *(float4*)(op + 4) = make_float4(acc[4], acc[5], acc[6], acc[7]);
    } else {
        // row-major fp16 (feeds next GEMM); 24B at 8B alignment -> 3x uint2
        _Float16* op = (_Float16*)out + (size_t)node * F + fb;
        __half2 h0 = __floats2half2_rn(acc[0], acc[1]);
        __half2 h1 = __floats2half2_rn(acc[2], acc[3]);
        __half2 h2 = __floats2half2_rn(acc[4], acc[5]);
        __half2 h3 = __floats2half2_rn(acc[6], acc[7]);
        *(uint2*)(op + 0) = make_uint2(*(unsigned*)&h0, *(unsigned*)&h1);
        *(uint2*)(op + 4) = make_uint2(*(unsigned*)&h2, *(unsigned*)&h3);
        if (SHW == 12) {
            __half2 h4 = __floats2half2_rn(acc[8], acc[9]);
            __half2 h5 = __floats2half2_rn(acc[10], acc[11]);
            *(uint2*)(op + 8) = make_uint2(*(unsigned*)&h4, *(unsigned*)&h5);
        }
    }
}

// ---------------- launch ----------------

extern "C" void kernel_launch(void* const* d_in, const int* in_sizes, int n_in,
                              void* d_out, int out_size, void* d_ws, size_t ws_size,
                              hipStream_t stream) {
    constexpr int IN = 128, H = 96, OUT = 64;

    const float* x   = (const float*)d_in[0];
    const int*   ei  = (const int*)d_in[1];
    const float* ew  = (const float*)d_in[2];
    const float* W1  = (const float*)d_in[3];
    const float* b1  = (const float*)d_in[4];
    const float* W2  = (const float*)d_in[5];
    const float* b2  = (const float*)d_in[6];
    const float* W3  = (const float*)d_in[7];
    const float* b3  = (const float*)d_in[8];
    const float* g1  = (const float*)d_in[9];
    const float* be1 = (const float*)d_in[10];
    const float* m1  = (const float*)d_in[11];
    const float* v1  = (const float*)d_in[12];
    const float* g2  = (const float*)d_in[13];
    const float* be2 = (const float*)d_in[14];
    const float* m2  = (const float*)d_in[15];
    const float* v2  = (const float*)d_in[16];

    const int N = in_sizes[0] / IN;   // 50000
    const int E = in_sizes[2];        // 800000
    const int* row_idx = ei;
    const int* col_idx = ei + E;

    char* ws = (char*)d_ws;
    size_t off = 0;
    auto alloc = [&](size_t bytes) -> void* {
        void* p = ws + off;
        off = (off + bytes + 255) & ~(size_t)255;
        return p;
    };
    unsigned long long* packed = (unsigned long long*)alloc((size_t)N * 8);
    float*     dis     = (float*)alloc((size_t)N * 4);
    int*       row_ptr = (int*)alloc((size_t)(N + 1) * 4);
    int*       bsum    = (int*)alloc(256 * 4);
    int*       boff    = (int*)alloc(256 * 4);
    int*       rank    = (int*)alloc((size_t)E * 4);
    unsigned*  ep      = (unsigned*)alloc((size_t)E * 4);
    _Float16*  wh      = (_Float16*)alloc((size_t)(H * IN + H * H + OUT * H) * 2);
    _Float16*  xws     = (_Float16*)alloc((size_t)8 * N * 16 * 2);  // shard gemm out
    _Float16*  rowbuf  = (_Float16*)alloc((size_t)N * H * 2);       // row-major aggr out
    (void)ws_size; (void)n_in; (void)out_size;

    _Float16* w1h = wh;
    _Float16* w2h = wh + (size_t)H * IN;
    _Float16* w3h = wh + (size_t)H * IN + (size_t)H * H;
    constexpr int W1N4 = H * IN / 4, W2N4 = H * H / 4, W3N4 = OUT * H / 4;

    const int NB = (N + 255) / 256;       // 196 (<= 256 for k_scan2)
    const int DEG_B = (E + 255) / 256;    // 3125
    const int CVT_B = (W1N4 + W2N4 + W3N4 + 255) / 256;

    hipMemsetAsync(packed, 0, (size_t)N * 8, stream);
    k_deg_cvt<<<DEG_B + CVT_B, 256, 0, stream>>>(col_idx, ew, packed, rank, E, DEG_B,
                                                 W1, W2, W3, wh, W1N4, W2N4, W3N4);
    k_scan1<<<NB, 256, 0, stream>>>(packed, bsum, dis, N);
    k_scan2<<<1, 256, 0, stream>>>(bsum, boff, NB);
    k_scan3<<<NB, 256, 0, stream>>>(packed, boff, row_ptr, N, E);
    k_fill<<<DEG_B, 256, 0, stream>>>(row_idx, col_idx, ew, dis, row_ptr, rank, ep, E);

    const int GG = (N / 16 + 3) / 4;      // 782: 4 waves/block, 16 nodes/wave
    const int GA = 8 * NB;                // shard-minor: shard = blockIdx & 7

    // layer 1 (fp32 x read directly, converted in-register)
    k_gemm<IN, H, 12, true><<<GG, 256, 0, stream>>>(x, w1h, xws, N);
    k_aggr<H, 12, true, false><<<GA, 256, 0, stream>>>(
        xws, row_ptr, ep, dis, b1, g1, be1, m1, v1, rowbuf, N);

    // layer 2
    k_gemm<H, H, 12, false><<<GG, 256, 0, stream>>>(rowbuf, w2h, xws, N);
    k_aggr<H, 12, true, false><<<GA, 256, 0, stream>>>(
        xws, row_ptr, ep, dis, b2, g2, be2, m2, v2, rowbuf, N);

    // layer 3
    k_gemm<H, OUT, 8, false><<<GG, 256, 0, stream>>>(rowbuf, w3h, xws, N);
    k_aggr<OUT, 8, false, true><<<GA, 256, 0, stream>>>(
        xws, row_ptr, ep, dis, b3, nullptr, nullptr, nullptr, nullptr, d_out, N);
}

// Round 9
// 281.365 us; speedup vs baseline: 1.3920x; 1.3920x over previous
//
#include <hip/hip_runtime.h>
#include <hip/hip_fp16.h>

// GCN 3-layer: x -> GCNConv(W1)+BN+ReLU -> GCNConv(W2)+BN+ReLU -> GCNConv(W3)
// CSR built once: 1 u64 atomic/edge -> {count, weighted-degree, in-bucket rank},
// atomic-free fill; edge record u32 {src:16 | norm fixed 2^-15:16}.
// Dense transforms: MFMA f16 16x16x32, wave = 16 nodes x F, fp32 accum,
// row-major fp16 output. Layer-1 GEMM is fused into the k_deg launch (atomic
// path and MFMA path are disjoint resources; no data dependency).
// Aggregation: thread = (node, 16B chunk) -> 12 lanes share one 192B source
// row (~2 line-touches/edge, the minimum). R8 lesson: per-(node,shard)
// mapping gives 64 lines/instruction and loses 2x despite lower HBM FETCH.

constexpr float BN_EPS = 1e-5f;
constexpr float FIXED_SCALE = 33554432.0f;        // 2^25 (weighted degree accum)
constexpr float INV_FIXED_SCALE = 1.0f / 33554432.0f;
constexpr float NORM_SCALE = 32768.0f;            // 2^15 (edge norm quant)
constexpr float INV_NORM_SCALE = 1.0f / 32768.0f;

typedef _Float16 f16x8 __attribute__((ext_vector_type(8)));
typedef float f32x4 __attribute__((ext_vector_type(4)));

// ---------------- MFMA GEMM body ----------------
// Y[n][f] = sum_k X[n][k] * W[f][k]; wave = 16 nodes x F features.
// A-frag: lane loads X[n0+(lane&15)][kt*32+(lane>>4)*8 ..+7].
// C/D: col = lane&15 (feature), row = (lane>>4)*4 + reg (node).

template <int K, int F, bool F32X, bool F32W>
__device__ __forceinline__ void gemm_body(const void* __restrict__ Xin,
                                          const void* __restrict__ Win,
                                          _Float16* __restrict__ Y, int n,
                                          int bid, int tid) {
    constexpr int KT = K / 32;
    constexpr int FT = F / 16;
    int wave = tid >> 6;
    int lane = tid & 63;
    int n0 = (bid * 4 + wave) * 16;
    if (n0 >= n) return;
    int quad = lane >> 4;
    int r = lane & 15;

    f16x8 a[KT];
    if (F32X) {
        const float* xr = (const float*)Xin + (size_t)(n0 + r) * K + quad * 8;
#pragma unroll
        for (int kt = 0; kt < KT; ++kt) {
            float4 v0 = *(const float4*)(xr + kt * 32);
            float4 v1 = *(const float4*)(xr + kt * 32 + 4);
            f16x8 t = {(_Float16)v0.x, (_Float16)v0.y, (_Float16)v0.z, (_Float16)v0.w,
                       (_Float16)v1.x, (_Float16)v1.y, (_Float16)v1.z, (_Float16)v1.w};
            a[kt] = t;
        }
    } else {
        const f16x8* xr = (const f16x8*)((const _Float16*)Xin + (size_t)(n0 + r) * K + quad * 8);
#pragma unroll
        for (int kt = 0; kt < KT; ++kt) a[kt] = xr[kt * 4];
    }

    f32x4 acc[FT];
#pragma unroll
    for (int ft = 0; ft < FT; ++ft) acc[ft] = (f32x4){0.f, 0.f, 0.f, 0.f};

#pragma unroll
    for (int kt = 0; kt < KT; ++kt) {
#pragma unroll
        for (int ft = 0; ft < FT; ++ft) {
            f16x8 b;
            if (F32W) {
                const float* wr = (const float*)Win + (size_t)(ft * 16 + r) * K + kt * 32 + quad * 8;
                float4 v0 = *(const float4*)wr;
                float4 v1 = *(const float4*)(wr + 4);
                f16x8 t = {(_Float16)v0.x, (_Float16)v0.y, (_Float16)v0.z, (_Float16)v0.w,
                           (_Float16)v1.x, (_Float16)v1.y, (_Float16)v1.z, (_Float16)v1.w};
                b = t;
            } else {
                b = *(const f16x8*)((const _Float16*)Win + (size_t)(ft * 16 + r) * K + kt * 32 + quad * 8);
            }
            acc[ft] = __builtin_amdgcn_mfma_f32_16x16x32_f16(a[kt], b, acc[ft], 0, 0, 0);
        }
    }

#pragma unroll
    for (int ft = 0; ft < FT; ++ft) {
#pragma unroll
        for (int reg = 0; reg < 4; ++reg) {
            int row = n0 + quad * 4 + reg;
            Y[(size_t)row * F + ft * 16 + r] = (_Float16)acc[ft][reg];
        }
    }
}

template <int K, int F>
__global__ __launch_bounds__(256) void k_gemm(const _Float16* __restrict__ X,
                                              const _Float16* __restrict__ Wh,
                                              _Float16* __restrict__ Y, int n) {
    gemm_body<K, F, false, false>(X, Wh, Y, n, blockIdx.x, threadIdx.x);
}

// ---------------- mega kernel: deg atomics + GEMM1 + W2/W3 convert ----------------

__global__ __launch_bounds__(256) void k_mega(
    const int* __restrict__ col_idx, const float* __restrict__ ew,
    unsigned long long* packed, int* rank, int e_cnt, int deg_b,
    const float* __restrict__ x, const float* __restrict__ W1,
    _Float16* __restrict__ bufA, int n, int gg,
    const float* __restrict__ W2, const float* __restrict__ W3,
    _Float16* __restrict__ w2h, _Float16* __restrict__ w3h,
    int w2n4, int w3n4) {
    int b = blockIdx.x;
    if (b < deg_b) {
        // one u64 atomic per edge; old>>32 = rank within dest bucket
        int e = b * 256 + threadIdx.x;
        if (e < e_cnt) {
            int c = col_idx[e];
            unsigned int wfix = (unsigned int)(ew[e] * FIXED_SCALE + 0.5f);
            unsigned long long inc = (1ull << 32) | (unsigned long long)wfix;
            unsigned long long old = atomicAdd(&packed[c], inc);
            rank[e] = (int)(old >> 32);
        }
    } else if (b < deg_b + gg) {
        gemm_body<128, 96, true, true>(x, W1, bufA, n, b - deg_b, threadIdx.x);
    } else {
        int i = (b - deg_b - gg) * 256 + threadIdx.x;   // float4 index
        const float* src;
        _Float16* dst;
        int off;
        if (i < w2n4) { src = W2; dst = w2h; off = i; }
        else if (i < w2n4 + w3n4) { src = W3; dst = w3h; off = i - w2n4; }
        else return;
        float4 v = ((const float4*)src)[off];
        __half2 h0 = __floats2half2_rn(v.x, v.y);
        __half2 h1 = __floats2half2_rn(v.z, v.w);
        *(uint2*)(dst + (size_t)off * 4) = make_uint2(*(unsigned*)&h0, *(unsigned*)&h1);
    }
}

// ---------------- scans ----------------

// block-sum of counts (hi32) + fused dis = rsqrt(1 + wsum)
__global__ void k_scan1(const unsigned long long* __restrict__ packed,
                        int* bsum, float* dis, int n) {
    __shared__ int s[256];
    int i = blockIdx.x * 256 + threadIdx.x;
    int cnt = 0;
    if (i < n) {
        unsigned long long p = packed[i];
        cnt = (int)(p >> 32);
        float wsum = (float)(unsigned int)(p & 0xffffffffull) * INV_FIXED_SCALE;
        dis[i] = rsqrtf(1.0f + wsum);   // self-loop weight 1 included
    }
    s[threadIdx.x] = cnt;
    __syncthreads();
    for (int off = 128; off > 0; off >>= 1) {
        if (threadIdx.x < off) s[threadIdx.x] += s[threadIdx.x + off];
        __syncthreads();
    }
    if (threadIdx.x == 0) bsum[blockIdx.x] = s[0];
}

// each block scans all 196 block-sums itself (merged scan2+scan3) -> row_ptr
__global__ void k_scan23(const unsigned long long* __restrict__ packed,
                         const int* __restrict__ bsum,
                         int* row_ptr, int n, int e_total, int nb) {
    __shared__ int sb[256];
    __shared__ int s[256];
    int t = threadIdx.x;
    int bv = (t < nb) ? bsum[t] : 0;
    sb[t] = bv;
    __syncthreads();
    for (int off = 1; off < 256; off <<= 1) {
        int x = (t >= off) ? sb[t - off] : 0;
        __syncthreads();
        sb[t] += x;
        __syncthreads();
    }
    int boff = (blockIdx.x == 0) ? 0 : sb[blockIdx.x - 1];   // exclusive

    int i = blockIdx.x * 256 + t;
    int v = (i < n) ? (int)(packed[i] >> 32) : 0;
    s[t] = v;
    __syncthreads();
    for (int off = 1; off < 256; off <<= 1) {
        int x = (t >= off) ? s[t - off] : 0;
        __syncthreads();
        s[t] += x;
        __syncthreads();
    }
    int ex = s[t] - v + boff;
    if (i < n) row_ptr[i] = ex;
    if (i == 0) row_ptr[n] = e_total;
}

// atomic-free fill: slot = row_ptr[dest] + rank; record = {src:16 | norm:16}
__global__ void k_fill(const int* __restrict__ row_idx, const int* __restrict__ col_idx,
                       const float* __restrict__ ew, const float* __restrict__ dis,
                       const int* __restrict__ row_ptr, const int* __restrict__ rank,
                       unsigned* ep, int e_cnt) {
    int e = blockIdx.x * 256 + threadIdx.x;
    if (e < e_cnt) {
        int r = row_idx[e];
        int c = col_idx[e];
        float nm = dis[r] * ew[e] * dis[c];
        unsigned q = (unsigned)(nm * NORM_SCALE + 0.5f);
        if (q > 65535u) q = 65535u;
        int p = row_ptr[c] + rank[e];
        ep[p] = ((unsigned)r << 16) | q;
    }
}

// ---------------- aggregation (gather fp16, accumulate fp32) ----------------
// thread = (node, 8-half chunk); 16B loads; the FQ lanes of one node read one
// contiguous row -> ~2 cache-line touches per edge (minimal).

__device__ inline void h8_acc(uint4 u, float w, float acc[8]) {
    float2 a = __half22float2(*(const __half2*)&u.x);
    float2 b = __half22float2(*(const __half2*)&u.y);
    float2 c = __half22float2(*(const __half2*)&u.z);
    float2 d = __half22float2(*(const __half2*)&u.w);
    acc[0] = fmaf(w, a.x, acc[0]); acc[1] = fmaf(w, a.y, acc[1]);
    acc[2] = fmaf(w, b.x, acc[2]); acc[3] = fmaf(w, b.y, acc[3]);
    acc[4] = fmaf(w, c.x, acc[4]); acc[5] = fmaf(w, c.y, acc[5]);
    acc[6] = fmaf(w, d.x, acc[6]); acc[7] = fmaf(w, d.y, acc[7]);
}

template <int F, bool BN, bool F32OUT>
__global__ __launch_bounds__(256) void k_aggr(
    const _Float16* __restrict__ xw, const int* __restrict__ row_ptr,
    const unsigned* __restrict__ ep,
    const float* __restrict__ dis, const float* __restrict__ bias,
    const float* __restrict__ g, const float* __restrict__ beta,
    const float* __restrict__ m, const float* __restrict__ v,
    void* __restrict__ out, int n) {
    constexpr int FQ = F / 8;      // 16B chunks per row: 12 (F=96) or 8 (F=64)
    int tg = blockIdx.x * 256 + threadIdx.x;
    int node = tg / FQ;
    int q = tg - node * FQ;
    if (node >= n) return;

    const uint4* __restrict__ base = (const uint4*)xw;   // row = FQ uint4s

    float acc[8];
    {
        float d = dis[node];
        float d2 = d * d;
        uint4 sv = base[(size_t)node * FQ + q];
        float t[8];
        h8_acc(sv, d2, (float*)memset(t, 0, sizeof(t)));
#pragma unroll
        for (int j = 0; j < 8; ++j) acc[j] = t[j];
    }

    int e0 = row_ptr[node], e1 = row_ptr[node + 1];
    int e = e0;
    for (; e + 4 <= e1; e += 4) {
        unsigned p0 = ep[e + 0], p1 = ep[e + 1], p2 = ep[e + 2], p3 = ep[e + 3];
        uint4 x0 = base[(size_t)(p0 >> 16) * FQ + q];
        uint4 x1 = base[(size_t)(p1 >> 16) * FQ + q];
        uint4 x2 = base[(size_t)(p2 >> 16) * FQ + q];
        uint4 x3 = base[(size_t)(p3 >> 16) * FQ + q];
        h8_acc(x0, (float)(p0 & 0xffffu) * INV_NORM_SCALE, acc);
        h8_acc(x1, (float)(p1 & 0xffffu) * INV_NORM_SCALE, acc);
        h8_acc(x2, (float)(p2 & 0xffffu) * INV_NORM_SCALE, acc);
        h8_acc(x3, (float)(p3 & 0xffffu) * INV_NORM_SCALE, acc);
    }
    for (; e < e1; ++e) {
        unsigned p = ep[e];
        uint4 xv = base[(size_t)(p >> 16) * FQ + q];
        h8_acc(xv, (float)(p & 0xffffu) * INV_NORM_SCALE, acc);
    }

    int fb = q * 8;
    const float4* bb = (const float4*)(bias + fb);
    float4 b0 = bb[0], b1 = bb[1];
    acc[0] += b0.x; acc[1] += b0.y; acc[2] += b0.z; acc[3] += b0.w;
    acc[4] += b1.x; acc[5] += b1.y; acc[6] += b1.z; acc[7] += b1.w;
    if (BN) {
        const float* gp = g + fb;
        const float* bp = beta + fb;
        const float* mp = m + fb;
        const float* vp = v + fb;
#pragma unroll
        for (int j = 0; j < 8; ++j) {
            acc[j] = fmaxf((acc[j] - mp[j]) * rsqrtf(vp[j] + BN_EPS) * gp[j] + bp[j], 0.f);
        }
    }
    if (F32OUT) {
        float* op = (float*)out + (size_t)node * F + fb;
        *(float4*)(op + 0) = make_float4(acc[0], acc[1], acc[2], acc[3]);
        *(float4*)(op + 4) = make_float4(acc[4], acc[5], acc[6], acc[7]);
    } else {
        __half2 h0 = __floats2half2_rn(acc[0], acc[1]);
        __half2 h1 = __floats2half2_rn(acc[2], acc[3]);
        __half2 h2 = __floats2half2_rn(acc[4], acc[5]);
        __half2 h3 = __floats2half2_rn(acc[6], acc[7]);
        uint4 u = make_uint4(*(unsigned*)&h0, *(unsigned*)&h1,
                             *(unsigned*)&h2, *(unsigned*)&h3);
        ((uint4*)out)[(size_t)node * FQ + q] = u;
    }
}

// ---------------- launch ----------------

extern "C" void kernel_launch(void* const* d_in, const int* in_sizes, int n_in,
                              void* d_out, int out_size, void* d_ws, size_t ws_size,
                              hipStream_t stream) {
    constexpr int IN = 128, H = 96, OUT = 64;

    const float* x   = (const float*)d_in[0];
    const int*   ei  = (const int*)d_in[1];
    const float* ew  = (const float*)d_in[2];
    const float* W1  = (const float*)d_in[3];
    const float* b1  = (const float*)d_in[4];
    const float* W2  = (const float*)d_in[5];
    const float* b2  = (const float*)d_in[6];
    const float* W3  = (const float*)d_in[7];
    const float* b3  = (const float*)d_in[8];
    const float* g1  = (const float*)d_in[9];
    const float* be1 = (const float*)d_in[10];
    const float* m1  = (const float*)d_in[11];
    const float* v1  = (const float*)d_in[12];
    const float* g2  = (const float*)d_in[13];
    const float* be2 = (const float*)d_in[14];
    const float* m2  = (const float*)d_in[15];
    const float* v2  = (const float*)d_in[16];

    const int N = in_sizes[0] / IN;   // 50000
    const int E = in_sizes[2];        // 800000
    const int* row_idx = ei;
    const int* col_idx = ei + E;

    char* ws = (char*)d_ws;
    size_t off = 0;
    auto alloc = [&](size_t bytes) -> void* {
        void* p = ws + off;
        off = (off + bytes + 255) & ~(size_t)255;
        return p;
    };
    unsigned long long* packed = (unsigned long long*)alloc((size_t)N * 8);
    float*     dis     = (float*)alloc((size_t)N * 4);
    int*       row_ptr = (int*)alloc((size_t)(N + 1) * 4);
    int*       bsum    = (int*)alloc(256 * 4);
    int*       rank    = (int*)alloc((size_t)E * 4);
    unsigned*  ep      = (unsigned*)alloc((size_t)E * 4);
    _Float16*  w2h     = (_Float16*)alloc((size_t)H * H * 2);
    _Float16*  w3h     = (_Float16*)alloc((size_t)OUT * H * 2);
    _Float16*  bufA    = (_Float16*)alloc((size_t)N * H * 2);   // gemm out
    _Float16*  bufB    = (_Float16*)alloc((size_t)N * H * 2);   // aggr out
    (void)ws_size; (void)n_in; (void)out_size;

    constexpr int W2N4 = H * H / 4, W3N4 = OUT * H / 4;
    const int NB = (N + 255) / 256;       // 196 (<= 256 for the merged scan)
    const int DEG_B = (E + 255) / 256;    // 3125
    const int GG = (N / 16 + 3) / 4;      // 782: 4 waves/block, 16 nodes/wave
    const int CVT_B = (W2N4 + W3N4 + 255) / 256;   // 15

    hipMemsetAsync(packed, 0, (size_t)N * 8, stream);
    k_mega<<<DEG_B + GG + CVT_B, 256, 0, stream>>>(
        col_idx, ew, packed, rank, E, DEG_B,
        x, W1, bufA, N, GG, W2, W3, w2h, w3h, W2N4, W3N4);
    k_scan1<<<NB, 256, 0, stream>>>(packed, bsum, dis, N);
    k_scan23<<<NB, 256, 0, stream>>>(packed, bsum, row_ptr, N, E, NB);
    k_fill<<<DEG_B, 256, 0, stream>>>(row_idx, col_idx, ew, dis, row_ptr, rank, ep, E);

    const int GA96 = ((size_t)N * (H / 8) + 255) / 256;
    const int GA64 = ((size_t)N * (OUT / 8) + 255) / 256;

    // layer 1 aggregation (gemm1 ran inside k_mega)
    k_aggr<H, true, false><<<GA96, 256, 0, stream>>>(
        bufA, row_ptr, ep, dis, b1, g1, be1, m1, v1, bufB, N);

    // layer 2
    k_gemm<H, H><<<GG, 256, 0, stream>>>(bufB, w2h, bufA, N);
    k_aggr<H, true, false><<<GA96, 256, 0, stream>>>(
        bufA, row_ptr, ep, dis, b2, g2, be2, m2, v2, bufB, N);

    // layer 3
    k_gemm<H, OUT><<<GG, 256, 0, stream>>>(bufB, w3h, bufA, N);
    k_aggr<OUT, false, true><<<GA64, 256, 0, stream>>>(
        bufA, row_ptr, ep, dis, b3, nullptr, nullptr, nullptr, nullptr, d_out, N);
}